// Round 5
// baseline (8425.830 us; speedup 1.0000x reference)
//
#include <hip/hip_runtime.h>

#define CC 64
#define NN 262144            // rows = 8 * 32*32*32
#define NELEM 16777216       // 8*64*32*32*32
#define KK 512
#define CHUNK 128            // codes per LDS chunk
#define NCHUNK 4
#define TAU 8e-5f
#define CAP 65536

typedef short short8 __attribute__((ext_vector_type(8)));
typedef float f32x4 __attribute__((ext_vector_type(4)));

__device__ __forceinline__ unsigned short bf16_rne(float x) {
    unsigned u = __float_as_uint(x);
    unsigned r = u + 0x7FFFu + ((u >> 16) & 1u);
    return (unsigned short)(r >> 16);
}
__device__ __forceinline__ float bf16_back(unsigned short h) {
    return __uint_as_float(((unsigned)h) << 16);
}

// ---------------------------------------------------------------------------
// Main kernel: split-bf16 MFMA scores + exact f32 t1 = A+B_k; argmin with
// tie-flagging. 1024 blocks x 256 thr; wave = 64 rows (4 row-tiles of 16).
// ---------------------------------------------------------------------------
__global__ __launch_bounds__(256, 2) void vq_mfma(
    const float* __restrict__ in, const float* __restrict__ cb,
    float* __restrict__ out_idx, double* __restrict__ partials,
    unsigned* __restrict__ cnt, unsigned* __restrict__ list)
{
#pragma clang fp contract(off)
    __shared__ short e1s[CHUNK * CC];      // 16 KB  bf16 hi
    __shared__ short e2s[CHUNK * CC];      // 16 KB  bf16 lo
    __shared__ float Bl[KK];               // 2 KB   exact numpy ||e_k||^2
    __shared__ float Al[256];              // 1 KB   exact numpy ||x_n||^2
    __shared__ double red_s[256];          // 2 KB

    const int tid  = threadIdx.x;
    const int lane = tid & 63;
    const int w    = tid >> 6;
    const int nb   = blockIdx.x * 256;
    const int bblk = nb >> 15;                       // uniform per block
    const float* xbase = in + ((size_t)bblk << 21) + (nb & 32767);

    // ---- exact A_n (numpy pairwise-8) for this block's 256 rows ----
    {
        const float* xa = xbase + tid;
        float r[8];
        #pragma unroll
        for (int j = 0; j < 8; ++j) { float v = xa[(size_t)j << 15]; r[j] = v * v; }
        #pragma unroll
        for (int i = 1; i < 8; ++i) {
            #pragma unroll
            for (int j = 0; j < 8; ++j) {
                float v = xa[(size_t)(8 * i + j) << 15];
                float sq = v * v;
                r[j] = r[j] + sq;
            }
        }
        Al[tid] = ((r[0] + r[1]) + (r[2] + r[3])) + ((r[4] + r[5]) + (r[6] + r[7]));
    }
    // ---- exact B_k (numpy pairwise-8) for all 512 codes ----
    #pragma unroll
    for (int kb = 0; kb < 2; ++kb) {
        const int k = tid + kb * 256;
        const float* ep = cb + k * CC;
        float q[8];
        #pragma unroll
        for (int j = 0; j < 8; ++j) { float v = ep[j]; q[j] = v * v; }
        #pragma unroll
        for (int i = 1; i < 8; ++i) {
            #pragma unroll
            for (int j = 0; j < 8; ++j) {
                float v = ep[8 * i + j];
                float sq = v * v;
                q[j] = q[j] + sq;
            }
        }
        Bl[k] = ((q[0] + q[1]) + (q[2] + q[3])) + ((q[4] + q[5]) + (q[6] + q[7]));
    }
    __syncthreads();

    // ---- per-lane exact-A cache for the 16 rows this lane's accs cover ----
    float Areg[4][4];
    #pragma unroll
    for (int rt = 0; rt < 4; ++rt)
        #pragma unroll
        for (int r = 0; r < 4; ++r)
            Areg[rt][r] = Al[w * 64 + rt * 16 + (lane >> 4) * 4 + r];

    // ---- A-fragments: rows nb+64w+16rt+(lane&15), channels (lane>>4)*8+j ----
    short8 a1[4][2], a2[4][2];
    {
        const int c0 = (lane >> 4) * 8;
        #pragma unroll
        for (int rt = 0; rt < 4; ++rt) {
            const int n = nb + w * 64 + rt * 16 + (lane & 15);
            const float* xp = in + ((size_t)(n >> 15) << 21) + (n & 32767);
            #pragma unroll
            for (int j = 0; j < 8; ++j) {
                float v0 = xp[(size_t)(c0 + j) << 15];
                float v1 = xp[(size_t)(c0 + j + 32) << 15];
                unsigned short h0 = bf16_rne(v0), h1 = bf16_rne(v1);
                a1[rt][0][j] = (short)h0;
                a1[rt][1][j] = (short)h1;
                a2[rt][0][j] = (short)bf16_rne(v0 - bf16_back(h0));
                a2[rt][1][j] = (short)bf16_rne(v1 - bf16_back(h1));
            }
        }
    }

    float    s1v[4][4];
    unsigned pk [4][4];
    #pragma unroll
    for (int rt = 0; rt < 4; ++rt)
        #pragma unroll
        for (int r = 0; r < 4; ++r) { s1v[rt][r] = 3.4e38f; pk[rt][r] = 0u; }

    for (int ch = 0; ch < NCHUNK; ++ch) {
        __syncthreads();
        // ---- stage 128 codes as bf16 hi/lo, XOR-swizzled 16B segs ----
        {
            const int code = tid & 127, hf = tid >> 7;
            const float* src = cb + (ch * CHUNK + code) * CC + hf * 32;
            #pragma unroll
            for (int s = 0; s < 4; ++s) {
                float4 v0 = ((const float4*)src)[s * 2];
                float4 v1 = ((const float4*)src)[s * 2 + 1];
                float vv[8] = {v0.x, v0.y, v0.z, v0.w, v1.x, v1.y, v1.z, v1.w};
                short8 hi, lo;
                #pragma unroll
                for (int j = 0; j < 8; ++j) {
                    unsigned short h = bf16_rne(vv[j]);
                    hi[j] = (short)h;
                    lo[j] = (short)bf16_rne(vv[j] - bf16_back(h));
                }
                int byteoff = code * 128 + ((hf * 4 + s) * 16 ^ ((code & 7) << 4));
                *(short8*)((char*)e1s + byteoff) = hi;
                *(short8*)((char*)e2s + byteoff) = lo;
            }
        }
        __syncthreads();

        #pragma unroll
        for (int t16 = 0; t16 < 8; ++t16) {
            const int kt = ch * 8 + t16;
            const int codeL = t16 * 16 + (lane & 15);
            short8 b1[2], b2[2];
            #pragma unroll
            for (int h = 0; h < 2; ++h) {
                int byteoff = codeL * 128 + ((4 * h + (lane >> 4)) * 16 ^ ((codeL & 7) << 4));
                b1[h] = *(const short8*)((const char*)e1s + byteoff);
                b2[h] = *(const short8*)((const char*)e2s + byteoff);
            }
            const float Bs = Bl[ch * CHUNK + codeL];
            #pragma unroll
            for (int rt = 0; rt < 4; ++rt) {
                f32x4 acc = {0.f, 0.f, 0.f, 0.f};
                acc = __builtin_amdgcn_mfma_f32_16x16x32_bf16(a1[rt][0], b1[0], acc, 0, 0, 0);
                acc = __builtin_amdgcn_mfma_f32_16x16x32_bf16(a1[rt][1], b1[1], acc, 0, 0, 0);
                acc = __builtin_amdgcn_mfma_f32_16x16x32_bf16(a2[rt][0], b1[0], acc, 0, 0, 0);
                acc = __builtin_amdgcn_mfma_f32_16x16x32_bf16(a2[rt][1], b1[1], acc, 0, 0, 0);
                acc = __builtin_amdgcn_mfma_f32_16x16x32_bf16(a1[rt][0], b2[0], acc, 0, 0, 0);
                acc = __builtin_amdgcn_mfma_f32_16x16x32_bf16(a1[rt][1], b2[1], acc, 0, 0, 0);
                #pragma unroll
                for (int r = 0; r < 4; ++r) {
                    float t1 = Areg[rt][r] + Bs;
                    float d  = __builtin_fmaf(-2.f, acc[r], t1);
                    float df = __builtin_fabsf(d - s1v[rt][r]);
                    unsigned p = pk[rt][r] | (df < TAU ? 0x80000000u : 0u);
                    bool u = d < s1v[rt][r];
                    pk[rt][r]  = u ? ((p & 0x80000000u) | (unsigned)kt) : p;
                    s1v[rt][r] = u ? d : s1v[rt][r];
                }
            }
        }
    }

    // ---- cross-lane argmin (16 codes/group) + flag merge + outputs ----
    double lsum = 0.0;
    #pragma unroll
    for (int rt = 0; rt < 4; ++rt) {
        #pragma unroll
        for (int r = 0; r < 4; ++r) {
            float s = s1v[rt][r];
            int code = (int)((pk[rt][r] & 31u) << 4) | (lane & 15);
            int fl = (int)(pk[rt][r] >> 31);
            #pragma unroll
            for (int off = 1; off < 16; off <<= 1) {
                float so = __shfl_xor(s, off);
                int   co = __shfl_xor(code, off);
                int   fo = __shfl_xor(fl, off);
                fl = fl | fo | (__builtin_fabsf(so - s) < TAU ? 1 : 0);
                if (so < s || (so == s && co < code)) { s = so; code = co; }
            }
            if ((lane & 15) == 0) {
                const int n = nb + w * 64 + rt * 16 + (lane >> 4) * 4 + r;
                out_idx[n] = (float)code;
                if (fl) {
                    unsigned pos = atomicAdd(cnt, 1u);
                    if (pos < CAP) list[pos] = (unsigned)n;
                }
                lsum += (double)s;
            }
        }
    }
    red_s[tid] = lsum;
    __syncthreads();
    for (int off = 128; off; off >>= 1) {
        if (tid < off) red_s[tid] += red_s[tid + off];
        __syncthreads();
    }
    if (tid == 0) partials[blockIdx.x] = red_s[0];
}

// ---------------------------------------------------------------------------
// Exact numpy-f32 recheck of flagged (near-tie) rows. One wave per row.
// ---------------------------------------------------------------------------
__global__ __launch_bounds__(64) void vq_recheck(
    const float* __restrict__ in, const float* __restrict__ cb,
    float* __restrict__ out_idx, const unsigned* __restrict__ cnt,
    const unsigned* __restrict__ list)
{
#pragma clang fp contract(off)
    const unsigned m = *cnt;
    const int lane = threadIdx.x;
    const unsigned total = (m <= CAP) ? m : NN;   // fallback: recheck all rows

    for (unsigned i = blockIdx.x; i < total; i += gridDim.x) {
        const unsigned n = (m <= CAP) ? list[i] : i;
        const float* xp = in + ((size_t)(n >> 15) << 21) + (n & 32767);
        float x[CC];
        #pragma unroll
        for (int c = 0; c < CC; ++c) x[c] = xp[(size_t)c << 15];

        float r[8];
        #pragma unroll
        for (int j = 0; j < 8; ++j) r[j] = x[j] * x[j];
        #pragma unroll
        for (int ii = 1; ii < 8; ++ii) {
            #pragma unroll
            for (int j = 0; j < 8; ++j) { float sq = x[8 * ii + j] * x[8 * ii + j]; r[j] = r[j] + sq; }
        }
        const float A = ((r[0] + r[1]) + (r[2] + r[3])) + ((r[4] + r[5]) + (r[6] + r[7]));

        float best = 3.4e38f; int bk = 0;
        for (int jj = 0; jj < 8; ++jj) {
            const int k = lane * 8 + jj;
            const float* e = cb + k * CC;
            float q[8];
            #pragma unroll
            for (int j = 0; j < 8; ++j) q[j] = e[j] * e[j];
            #pragma unroll
            for (int ii = 1; ii < 8; ++ii) {
                #pragma unroll
                for (int j = 0; j < 8; ++j) { float sq = e[8 * ii + j] * e[8 * ii + j]; q[j] = q[j] + sq; }
            }
            const float B = ((q[0] + q[1]) + (q[2] + q[3])) + ((q[4] + q[5]) + (q[6] + q[7]));
            float cacc = 0.f;
            #pragma unroll
            for (int c = 0; c < CC; ++c) cacc = __builtin_fmaf(x[c], e[c], cacc);
            const float t1 = A + B;
            const float t2 = 2.0f * cacc;
            const float D = t1 - t2;
            if (D < best) { best = D; bk = k; }
        }
        #pragma unroll
        for (int off = 1; off < 64; off <<= 1) {
            float bo = __shfl_xor(best, off);
            int   ko = __shfl_xor(bk, off);
            if (bo < best || (bo == best && ko < bk)) { best = bo; bk = ko; }
        }
        if (lane == 0) out_idx[n] = (float)bk;
    }
}

__global__ __launch_bounds__(256) void vq_out(
    const float* __restrict__ cb, const float* __restrict__ out_idx_f,
    float* __restrict__ out_q, float* __restrict__ out_loss,
    const double* __restrict__ partials)
{
    __shared__ double rs[256];
    const int tid = threadIdx.x;
    const int n = blockIdx.x * 256 + tid;
    const int idx = (int)out_idx_f[n];
    const int b = n >> 15, sp = n & 32767;
    float* qp = out_q + ((size_t)b << 21) + sp;
    const float* e = cb + idx * CC;
    #pragma unroll
    for (int c = 0; c < CC; c += 4) {
        float4 ev = *(const float4*)&e[c];
        qp[(size_t)(c + 0) << 15] = ev.x;
        qp[(size_t)(c + 1) << 15] = ev.y;
        qp[(size_t)(c + 2) << 15] = ev.z;
        qp[(size_t)(c + 3) << 15] = ev.w;
    }

    if (blockIdx.x == 0) {
        double s = partials[tid] + partials[tid + 256] + partials[tid + 512] + partials[tid + 768];
        rs[tid] = s;
        __syncthreads();
        for (int off = 128; off; off >>= 1) {
            if (tid < off) rs[tid] += rs[tid + off];
            __syncthreads();
        }
        if (tid == 0) *out_loss = (float)(1.25 * rs[0] / (double)NELEM);
    }
}

__global__ void vq_init(unsigned* cnt) { *cnt = 0u; }

extern "C" void kernel_launch(void* const* d_in, const int* in_sizes, int n_in,
                              void* d_out, int out_size, void* d_ws, size_t ws_size,
                              hipStream_t stream) {
    const float* in = (const float*)d_in[0];
    const float* cb = (const float*)d_in[1];
    float* out      = (float*)d_out;
    float* out_q    = out;                    // [8,64,32,32,32] = 16777216
    float* out_loss = out + NELEM;            // scalar
    float* out_idx  = out + NELEM + 1;        // [262144]

    unsigned char* ws = (unsigned char*)d_ws;
    unsigned* cnt     = (unsigned*)ws;
    double* partials  = (double*)(ws + 64);
    unsigned* list    = (unsigned*)(ws + 16384);

    vq_init<<<1, 1, 0, stream>>>(cnt);
    vq_mfma<<<NN / 256, 256, 0, stream>>>(in, cb, out_idx, partials, cnt, list);
    vq_recheck<<<2048, 64, 0, stream>>>(in, cb, out_idx, cnt, list);
    vq_out<<<NN / 256, 256, 0, stream>>>(cb, out_idx, out_q, out_loss, partials);
}

// Round 6
// 201.402 us; speedup vs baseline: 41.8359x; 41.8359x over previous
//
#include <hip/hip_runtime.h>

#define CC 64
#define NN 262144            // rows = 8 * 32*32*32
#define NELEM 16777216       // 8*64*32*32*32
#define KK 512
#define CHUNK 128            // codes per LDS chunk
#define NCHUNK 4
#define TAU 5e-5f
#define CAP 65536

typedef short short8 __attribute__((ext_vector_type(8)));
typedef float f32x4 __attribute__((ext_vector_type(4)));

__device__ __forceinline__ unsigned short bf16_rne(float x) {
    unsigned u = __float_as_uint(x);
    unsigned r = u + 0x7FFFu + ((u >> 16) & 1u);
    return (unsigned short)(r >> 16);
}
__device__ __forceinline__ float bf16_back(unsigned short h) {
    return __uint_as_float(((unsigned)h) << 16);
}

// ---------------------------------------------------------------------------
// Main kernel: split-bf16 MFMA scores + exact f32 t1 = A+B_k; top-2 tracking;
// rows with top-2 gap < TAU get exact-numpy recheck in a second kernel.
// ---------------------------------------------------------------------------
__global__ __launch_bounds__(256, 2) void vq_mfma(
    const float* __restrict__ in, const float* __restrict__ cb,
    float* __restrict__ out_idx, double* __restrict__ partials,
    unsigned* __restrict__ cnt, unsigned* __restrict__ list)
{
#pragma clang fp contract(off)
    __shared__ short e1s[CHUNK * CC];      // 16 KB  bf16 hi
    __shared__ short e2s[CHUNK * CC];      // 16 KB  bf16 lo
    __shared__ float Bl[KK];               // 2 KB   exact numpy ||e_k||^2
    __shared__ float Al[256];              // 1 KB   exact numpy ||x_n||^2
    __shared__ double red_s[256];          // 2 KB

    const int tid  = threadIdx.x;
    const int lane = tid & 63;
    const int w    = tid >> 6;
    const int nb   = blockIdx.x * 256;
    const int bblk = nb >> 15;                       // uniform per block
    const float* xbase = in + ((size_t)bblk << 21) + (nb & 32767);

    // ---- exact A_n (numpy pairwise-8) for this block's 256 rows ----
    {
        const float* xa = xbase + tid;
        float r[8];
        #pragma unroll
        for (int j = 0; j < 8; ++j) { float v = xa[(size_t)j << 15]; r[j] = v * v; }
        #pragma unroll
        for (int i = 1; i < 8; ++i) {
            #pragma unroll
            for (int j = 0; j < 8; ++j) {
                float v = xa[(size_t)(8 * i + j) << 15];
                float sq = v * v;
                r[j] = r[j] + sq;
            }
        }
        Al[tid] = ((r[0] + r[1]) + (r[2] + r[3])) + ((r[4] + r[5]) + (r[6] + r[7]));
    }
    // ---- exact B_k (numpy pairwise-8) for all 512 codes ----
    #pragma unroll
    for (int kb = 0; kb < 2; ++kb) {
        const int k = tid + kb * 256;
        const float* ep = cb + k * CC;
        float q[8];
        #pragma unroll
        for (int j = 0; j < 8; ++j) { float v = ep[j]; q[j] = v * v; }
        #pragma unroll
        for (int i = 1; i < 8; ++i) {
            #pragma unroll
            for (int j = 0; j < 8; ++j) {
                float v = ep[8 * i + j];
                float sq = v * v;
                q[j] = q[j] + sq;
            }
        }
        Bl[k] = ((q[0] + q[1]) + (q[2] + q[3])) + ((q[4] + q[5]) + (q[6] + q[7]));
    }
    __syncthreads();

    // ---- per-lane exact-A cache for the 16 rows this lane's accs cover ----
    float Areg[4][4];
    #pragma unroll
    for (int rt = 0; rt < 4; ++rt)
        #pragma unroll
        for (int r = 0; r < 4; ++r)
            Areg[rt][r] = Al[w * 64 + rt * 16 + (lane >> 4) * 4 + r];

    // ---- A-fragments: rows nb+64w+16rt+(lane&15), channels (lane>>4)*8+j ----
    short8 a1[4][2], a2[4][2];
    {
        const int c0 = (lane >> 4) * 8;
        #pragma unroll
        for (int rt = 0; rt < 4; ++rt) {
            const int n = nb + w * 64 + rt * 16 + (lane & 15);
            const float* xp = in + ((size_t)(n >> 15) << 21) + (n & 32767);
            #pragma unroll
            for (int j = 0; j < 8; ++j) {
                float v0 = xp[(size_t)(c0 + j) << 15];
                float v1 = xp[(size_t)(c0 + j + 32) << 15];
                unsigned short h0 = bf16_rne(v0), h1 = bf16_rne(v1);
                a1[rt][0][j] = (short)h0;
                a1[rt][1][j] = (short)h1;
                a2[rt][0][j] = (short)bf16_rne(v0 - bf16_back(h0));
                a2[rt][1][j] = (short)bf16_rne(v1 - bf16_back(h1));
            }
        }
    }

    float    s1v[4][4], s2v[4][4];
    unsigned pk [4][4];
    #pragma unroll
    for (int rt = 0; rt < 4; ++rt)
        #pragma unroll
        for (int r = 0; r < 4; ++r) { s1v[rt][r] = 3.4e38f; s2v[rt][r] = 3.4e38f; pk[rt][r] = 0u; }

    for (int ch = 0; ch < NCHUNK; ++ch) {
        __syncthreads();
        // ---- stage 128 codes as bf16 hi/lo, XOR-swizzled 16B segs ----
        {
            const int code = tid & 127, hf = tid >> 7;
            const float* src = cb + (ch * CHUNK + code) * CC + hf * 32;
            #pragma unroll
            for (int s = 0; s < 4; ++s) {
                float4 v0 = ((const float4*)src)[s * 2];
                float4 v1 = ((const float4*)src)[s * 2 + 1];
                float vv[8] = {v0.x, v0.y, v0.z, v0.w, v1.x, v1.y, v1.z, v1.w};
                short8 hi, lo;
                #pragma unroll
                for (int j = 0; j < 8; ++j) {
                    unsigned short h = bf16_rne(vv[j]);
                    hi[j] = (short)h;
                    lo[j] = (short)bf16_rne(vv[j] - bf16_back(h));
                }
                int byteoff = code * 128 + ((hf * 4 + s) * 16 ^ ((code & 7) << 4));
                *(short8*)((char*)e1s + byteoff) = hi;
                *(short8*)((char*)e2s + byteoff) = lo;
            }
        }
        __syncthreads();

        #pragma unroll
        for (int t16 = 0; t16 < 8; ++t16) {
            const int kt = ch * 8 + t16;
            const int codeL = t16 * 16 + (lane & 15);
            short8 b1[2], b2[2];
            #pragma unroll
            for (int h = 0; h < 2; ++h) {
                int byteoff = codeL * 128 + ((4 * h + (lane >> 4)) * 16 ^ ((codeL & 7) << 4));
                b1[h] = *(const short8*)((const char*)e1s + byteoff);
                b2[h] = *(const short8*)((const char*)e2s + byteoff);
            }
            const float Bs = Bl[ch * CHUNK + codeL];
            #pragma unroll
            for (int rt = 0; rt < 4; ++rt) {
                f32x4 acc = {0.f, 0.f, 0.f, 0.f};
                acc = __builtin_amdgcn_mfma_f32_16x16x32_bf16(a1[rt][0], b1[0], acc, 0, 0, 0);
                acc = __builtin_amdgcn_mfma_f32_16x16x32_bf16(a1[rt][1], b1[1], acc, 0, 0, 0);
                acc = __builtin_amdgcn_mfma_f32_16x16x32_bf16(a2[rt][0], b1[0], acc, 0, 0, 0);
                acc = __builtin_amdgcn_mfma_f32_16x16x32_bf16(a2[rt][1], b1[1], acc, 0, 0, 0);
                acc = __builtin_amdgcn_mfma_f32_16x16x32_bf16(a1[rt][0], b2[0], acc, 0, 0, 0);
                acc = __builtin_amdgcn_mfma_f32_16x16x32_bf16(a1[rt][1], b2[1], acc, 0, 0, 0);
                #pragma unroll
                for (int r = 0; r < 4; ++r) {
                    float t1 = Areg[rt][r] + Bs;
                    float d  = __builtin_fmaf(-2.f, acc[r], t1);
                    bool u = d < s1v[rt][r];
                    s2v[rt][r] = u ? s1v[rt][r] : __builtin_fminf(s2v[rt][r], d);
                    pk [rt][r] = u ? (unsigned)kt : pk[rt][r];
                    s1v[rt][r] = u ? d : s1v[rt][r];
                }
            }
        }
    }

    // ---- cross-lane top-2 merge (16 codes/group) + outputs ----
    double lsum = 0.0;
    #pragma unroll
    for (int rt = 0; rt < 4; ++rt) {
        #pragma unroll
        for (int r = 0; r < 4; ++r) {
            float s1 = s1v[rt][r], s2 = s2v[rt][r];
            int c1 = (int)(pk[rt][r] << 4) | (lane & 15);
            #pragma unroll
            for (int off = 1; off < 16; off <<= 1) {
                float s1o = __shfl_xor(s1, off);
                float s2o = __shfl_xor(s2, off);
                int   c1o = __shfl_xor(c1, off);
                if (s1o < s1 || (s1o == s1 && c1o < c1)) {
                    s2 = __builtin_fminf(s1, s2o);
                    s1 = s1o; c1 = c1o;
                } else {
                    s2 = __builtin_fminf(s2, s1o);
                }
            }
            if ((lane & 15) == 0) {
                const int n = nb + w * 64 + rt * 16 + (lane >> 4) * 4 + r;
                out_idx[n] = (float)c1;
                if (s2 - s1 < TAU) {
                    unsigned pos = atomicAdd(cnt, 1u);
                    if (pos < CAP) list[pos] = (unsigned)n;
                }
                lsum += (double)s1;
            }
        }
    }
    red_s[tid] = lsum;
    __syncthreads();
    for (int off = 128; off; off >>= 1) {
        if (tid < off) red_s[tid] += red_s[tid + off];
        __syncthreads();
    }
    if (tid == 0) partials[blockIdx.x] = red_s[0];
}

// ---------------------------------------------------------------------------
// Exact numpy-f32 recheck of flagged (near-tie) rows. One wave per row.
// ---------------------------------------------------------------------------
__global__ __launch_bounds__(64) void vq_recheck(
    const float* __restrict__ in, const float* __restrict__ cb,
    float* __restrict__ out_idx, const unsigned* __restrict__ cnt,
    const unsigned* __restrict__ list)
{
#pragma clang fp contract(off)
    const unsigned m = *cnt;
    const int lane = threadIdx.x;
    const unsigned total = (m <= CAP) ? m : NN;   // fallback: recheck all rows

    for (unsigned i = blockIdx.x; i < total; i += gridDim.x) {
        const unsigned n = (m <= CAP) ? list[i] : i;
        const float* xp = in + ((size_t)(n >> 15) << 21) + (n & 32767);
        float x[CC];
        #pragma unroll
        for (int c = 0; c < CC; ++c) x[c] = xp[(size_t)c << 15];

        float r[8];
        #pragma unroll
        for (int j = 0; j < 8; ++j) r[j] = x[j] * x[j];
        #pragma unroll
        for (int ii = 1; ii < 8; ++ii) {
            #pragma unroll
            for (int j = 0; j < 8; ++j) { float sq = x[8 * ii + j] * x[8 * ii + j]; r[j] = r[j] + sq; }
        }
        const float A = ((r[0] + r[1]) + (r[2] + r[3])) + ((r[4] + r[5]) + (r[6] + r[7]));

        float best = 3.4e38f; int bk = 0;
        for (int jj = 0; jj < 8; ++jj) {
            const int k = lane * 8 + jj;
            const float* e = cb + k * CC;
            float q[8];
            #pragma unroll
            for (int j = 0; j < 8; ++j) q[j] = e[j] * e[j];
            #pragma unroll
            for (int ii = 1; ii < 8; ++ii) {
                #pragma unroll
                for (int j = 0; j < 8; ++j) { float sq = e[8 * ii + j] * e[8 * ii + j]; q[j] = q[j] + sq; }
            }
            const float B = ((q[0] + q[1]) + (q[2] + q[3])) + ((q[4] + q[5]) + (q[6] + q[7]));
            float cacc = 0.f;
            #pragma unroll
            for (int c = 0; c < CC; ++c) cacc = __builtin_fmaf(x[c], e[c], cacc);
            const float t1 = A + B;
            const float t2 = 2.0f * cacc;
            const float D = t1 - t2;
            if (D < best) { best = D; bk = k; }
        }
        #pragma unroll
        for (int off = 1; off < 64; off <<= 1) {
            float bo = __shfl_xor(best, off);
            int   ko = __shfl_xor(bk, off);
            if (bo < best || (bo == best && ko < bk)) { best = bo; bk = ko; }
        }
        if (lane == 0) out_idx[n] = (float)bk;
    }
}

__global__ __launch_bounds__(256) void vq_out(
    const float* __restrict__ cb, const float* __restrict__ out_idx_f,
    float* __restrict__ out_q, float* __restrict__ out_loss,
    const double* __restrict__ partials)
{
    __shared__ double rs[256];
    const int tid = threadIdx.x;
    const int n = blockIdx.x * 256 + tid;
    const int idx = (int)out_idx_f[n];
    const int b = n >> 15, sp = n & 32767;
    float* qp = out_q + ((size_t)b << 21) + sp;
    const float* e = cb + idx * CC;
    #pragma unroll
    for (int c = 0; c < CC; c += 4) {
        float4 ev = *(const float4*)&e[c];
        qp[(size_t)(c + 0) << 15] = ev.x;
        qp[(size_t)(c + 1) << 15] = ev.y;
        qp[(size_t)(c + 2) << 15] = ev.z;
        qp[(size_t)(c + 3) << 15] = ev.w;
    }

    if (blockIdx.x == 0) {
        double s = partials[tid] + partials[tid + 256] + partials[tid + 512] + partials[tid + 768];
        rs[tid] = s;
        __syncthreads();
        for (int off = 128; off; off >>= 1) {
            if (tid < off) rs[tid] += rs[tid + off];
            __syncthreads();
        }
        if (tid == 0) *out_loss = (float)(1.25 * rs[0] / (double)NELEM);
    }
}

__global__ void vq_init(unsigned* cnt) { *cnt = 0u; }

extern "C" void kernel_launch(void* const* d_in, const int* in_sizes, int n_in,
                              void* d_out, int out_size, void* d_ws, size_t ws_size,
                              hipStream_t stream) {
    const float* in = (const float*)d_in[0];
    const float* cb = (const float*)d_in[1];
    float* out      = (float*)d_out;
    float* out_q    = out;                    // [8,64,32,32,32] = 16777216
    float* out_loss = out + NELEM;            // scalar
    float* out_idx  = out + NELEM + 1;        // [262144]

    unsigned char* ws = (unsigned char*)d_ws;
    unsigned* cnt     = (unsigned*)ws;
    double* partials  = (double*)(ws + 64);
    unsigned* list    = (unsigned*)(ws + 16384);

    vq_init<<<1, 1, 0, stream>>>(cnt);
    vq_mfma<<<NN / 256, 256, 0, stream>>>(in, cb, out_idx, partials, cnt, list);
    vq_recheck<<<2048, 64, 0, stream>>>(in, cb, out_idx, cnt, list);
    vq_out<<<NN / 256, 256, 0, stream>>>(cb, out_idx, out_q, out_loss, partials);
}